// Round 8
// baseline (5463.778 us; speedup 1.0000x reference)
//
#include <hip/hip_runtime.h>
#include <hip/hip_bf16.h>

#define TT 512
#define BB 128
#define HH 512
#define NGROUP 8          // batch groups, 16 rows each
#define NSLICE 8          // col-slice blocks per group (4 waves x 16 cols each)
#define GPB 2             // groups per block (interleaved chains)
#define ALPHA 0.1f
#define NOISE_S 0.02f

typedef __attribute__((ext_vector_type(8))) short short8;
typedef __attribute__((ext_vector_type(8))) _Float16 half8;
typedef __attribute__((ext_vector_type(4))) float f32x4;

// ---- workspace layout (bytes) ----
#define WPACK_CH 132096                       // 16B chunks of packed weights
#define PUB1_B (WPACK_CH * 16)                // tanh1 pub: [NGROUP][8192] u32 words
#define PUB2_B (PUB1_B + NGROUP * 32768)      // tanh2 pub: [NGROUP][8192] u32 words
// word = (step_tag << 16) | fp16_bits ; word idx = kt*512 + srow*8 + j

__device__ __forceinline__ unsigned short f2h(float f) {
  return __builtin_bit_cast(unsigned short, (_Float16)f);  // RNE
}

__device__ __forceinline__ float fast_tanh(float x) {
  float e = __builtin_amdgcn_exp2f(x * 2.8853900817779268f);
  return 1.0f - 2.0f * __builtin_amdgcn_rcpf(e + 1.0f);
}

__device__ __forceinline__ f32x4 mfma16(short8 a, short8 b, f32x4 c) {
  return __builtin_amdgcn_mfma_f32_16x16x32_f16(
      __builtin_bit_cast(half8, a), __builtin_bit_cast(half8, b), c, 0, 0, 0);
}

// ---------------------------------------------------------------------------
// Pack fp32 weights into fp16 MFMA B-fragment chunk order.
// chunk(kt, nt, lane)[i] = W[kt*32 + (lane>>4)*8 + i][nt*16 + (lane&15)]
//   WA = [wrec11; wrec12] (K=1024)  chunks [0, 65536)
//   WB = [wrec21; wrec22] (K=1024)  chunks [65536, 131072)
//   WO = wo padded to N=16 (K=512)  chunks [131072, 132096)
// ---------------------------------------------------------------------------
__global__ void pack_weights(const float* __restrict__ w11, const float* __restrict__ w12,
                             const float* __restrict__ w21, const float* __restrict__ w22,
                             const float* __restrict__ wo, unsigned short* __restrict__ dst) {
  int idx = blockIdx.x * 256 + threadIdx.x;
  if (idx < 131072) {
    int which = idx >> 16;
    int c0 = idx & 65535;
    int kt = c0 >> 11, rem = c0 & 2047;
    int nt = rem >> 6, lane = rem & 63;
    const float* wlo = which ? w21 : w11;   // k < 512  (multiplies tanh(h1))
    const float* whi = which ? w22 : w12;   // k >= 512 (multiplies tanh(h2))
    unsigned short* p = dst + (size_t)idx * 8;
    int n = nt * 16 + (lane & 15);
    int kb = kt * 32 + ((lane >> 4) & 3) * 8;
#pragma unroll
    for (int i = 0; i < 8; ++i) {
      int k = kb + i;
      float v = (k < HH) ? wlo[k * HH + n] : whi[(k - HH) * HH + n];
      p[i] = f2h(v);
    }
  } else if (idx < 132096) {
    int c0 = idx - 131072;
    int kt = c0 >> 6, lane = c0 & 63;
    unsigned short* p = dst + (size_t)131072 * 8 + (size_t)c0 * 8;
    int n = lane & 15;
    int kb = kt * 32 + ((lane >> 4) & 3) * 8;
#pragma unroll
    for (int i = 0; i < 8; ++i) {
      float v = (n < 3) ? wo[(kb + i) * 3 + n] : 0.0f;
      p[i] = f2h(v);
    }
  }
}

// zero pub1+pub2 each launch (tag 0 == initial state h=0, graph-replay safe)
__global__ void zero_ws(int* __restrict__ p, int n) {
  for (int i = blockIdx.x * 256 + threadIdx.x; i < n; i += gridDim.x * 256)
    p[i] = 0;
}

// ---------------------------------------------------------------------------
// Sliced persistent RNN; tag-in-data sync; TWO interleaved group-chains per
// block to hide cross-XCD visibility latency. Grid: 32 blocks = NSLICE(8) x
// NPAIR(4); block handles groups gp and gp+4. Per step:
//   A(g0) A(g1) B(g0) B(g1)
// so each publish->poll gap contains a full phase of the other chain.
// Phase A(g): W11xT1[g] -> poll/stage pub2[g](>=t) -> W12xT2[g] (+rotated
//   out[t-1]) -> h1 update -> publish pub1[g] tag t+1.
// Phase B(g): W22xT2[g] -> poll/stage pub1[g](>=t+1) -> W21xT1'[g] ->
//   h2 update -> publish pub2[g] tag t+1.
// WAR-safe per chain (same argument as before; interleave preserves
// per-group ordering).
// ---------------------------------------------------------------------------
__global__ __launch_bounds__(256, 1)
void rnn_main(const float* __restrict__ x, const float* __restrict__ wi_stim,
              const float* __restrict__ wi_ctx, const float* __restrict__ noise1,
              const float* __restrict__ noise2, char* __restrict__ ws,
              float* __restrict__ out) {
  __shared__ __align__(16) unsigned short T1buf[2][16 * 512];  // tanh(h1) per group
  __shared__ __align__(16) unsigned short T2buf[2][16 * 512];  // tanh(h2) per group
  __shared__ __align__(16) unsigned short WOlds[16 * 512];     // wo B-chunks
  __shared__ float xstage[2][2][16][5];                        // [buf][gi][row][c]

  const int tid = threadIdx.x;
  const int w = tid >> 6, lane = tid & 63;
  const int c16 = lane & 15, kh = lane >> 4;
  const int slice = blockIdx.x >> 2;     // 0..7
  const int gp = blockIdx.x & 3;         // 0..3 ; groups gp, gp+4
  const int nt = slice * 4 + w;          // n-tile 0..31
  const int n0 = nt * 16;
  const int lrow0 = kh * 4;

  const short8* __restrict__ WC = (const short8*)ws;
  unsigned* const pub1g[2] = {(unsigned*)(ws + PUB1_B) + gp * 8192,
                              (unsigned*)(ws + PUB1_B) + (gp + 4) * 8192};
  unsigned* const pub2g[2] = {(unsigned*)(ws + PUB2_B) + gp * 8192,
                              (unsigned*)(ws + PUB2_B) + (gp + 4) * 8192};
  const int b0g[2] = {gp * 16, (gp + 4) * 16};

  // ---- init LDS ----
  short8 z = {0, 0, 0, 0, 0, 0, 0, 0};
  for (int i = tid; i < 2048; i += 256) {
    ((short8*)T1buf)[i] = z;             // tanh(0) = 0
    ((short8*)T2buf)[i] = z;
  }
#pragma unroll
  for (int c = 0; c < 4; ++c) {          // wo fragments to LDS (all blocks)
    int kt = w * 4 + c;
    short8 v = WC[131072 + kt * 64 + lane];
    *(short8*)&WOlds[kt * 512 + lane * 8] = v;
  }
  if (tid < 160) {
    int gi = tid / 80, rem = tid % 80;
    int b = rem / 5, c = rem % 5;
    xstage[0][gi][b][c] = x[((size_t)(b0g[gi] + b) * TT + 0) * 5 + c];
  }

  // ---- weights to VGPRs, pinned resident (shared by both groups) ----
  short8 wA[32], wB[32];
#pragma unroll
  for (int kt = 0; kt < 32; ++kt) {
    wA[kt] = WC[kt * 2048 + nt * 64 + lane];
    wB[kt] = WC[65536 + kt * 2048 + nt * 64 + lane];
  }
#pragma unroll
  for (int kt = 0; kt < 32; ++kt) {
    asm volatile("" : "+v"(wA[kt]));
    asm volatile("" : "+v"(wB[kt]));
  }

  float wis[3], wic[2];
#pragma unroll
  for (int c = 0; c < 3; ++c) wis[c] = wi_stim[c * HH + n0 + c16];
#pragma unroll
  for (int c = 0; c < 2; ++c) wic[c] = wi_ctx[c * HH + n0 + c16];

  float h1[2][4] = {{0, 0, 0, 0}, {0, 0, 0, 0}};
  float h2[2][4] = {{0, 0, 0, 0}, {0, 0, 0, 0}};

  // publish address components: value (row=lrow0+r, col=n0+c16) -> chunk slot
  const int kt_p = nt >> 1;
  const int hi = (((nt & 1) * 16) + c16) >> 3;
  const int ci = c16 & 7;
  const int pslot = kt_p * 512 + (lrow0 + hi * 16) * 8 + ci;  // +r*8

  // poll own gather words until all tags >= exp, then unpack into LDS
  auto stage_poll = [&](const unsigned* pubw, unsigned short* Tbuf, unsigned exp) {
    unsigned long long v[4][4];
    bool ok;
    do {
      ok = true;
#pragma unroll
      for (int c = 0; c < 4; ++c) {
        const unsigned long long* src =
            (const unsigned long long*)(pubw + ((w * 4 + c) << 9)) + lane * 4;
#pragma unroll
        for (int j = 0; j < 4; ++j) {
          v[c][j] = __hip_atomic_load(&src[j], __ATOMIC_RELAXED,
                                      __HIP_MEMORY_SCOPE_AGENT);
          ok &= (((unsigned)(v[c][j] >> 16) & 0xffffu) >= exp);
          ok &= ((unsigned)(v[c][j] >> 48) >= exp);
        }
      }
    } while (!ok);
    __builtin_amdgcn_sched_barrier(0);
    asm volatile("" ::: "memory");
#pragma unroll
    for (int c = 0; c < 4; ++c) {
      unsigned long long u0 = (v[c][0] & 0xffffull)
                            | (((v[c][0] >> 32) & 0xffffull) << 16)
                            | ((v[c][1] & 0xffffull) << 32)
                            | (((v[c][1] >> 32) & 0xffffull) << 48);
      unsigned long long u1 = (v[c][2] & 0xffffull)
                            | (((v[c][2] >> 32) & 0xffffull) << 16)
                            | ((v[c][3] & 0xffffull) << 32)
                            | (((v[c][3] >> 32) & 0xffffull) << 48);
      *(unsigned long long*)&Tbuf[(w * 4 + c) * 512 + lane * 8] = u0;
      *(unsigned long long*)&Tbuf[(w * 4 + c) * 512 + lane * 8 + 4] = u1;
    }
  };

  __syncthreads();

  for (int t = 0; t < TT; ++t) {
    const int buf = t & 1;
    const unsigned tagN = (unsigned)(t + 1) << 16;

    // ================= phase A: both chains =================
#pragma unroll
    for (int gi = 0; gi < 2; ++gi) {
      float n1v[4];
#pragma unroll
      for (int r = 0; r < 4; ++r)
        n1v[r] = noise1[((size_t)t * BB + b0g[gi] + lrow0 + r) * HH + n0 + c16];

      f32x4 aA = {0, 0, 0, 0}, aB = {0, 0, 0, 0};
#pragma unroll
      for (int kt = 0; kt < 16; ++kt) {  // W11 x T1 (local, stable)
        short8 a1 = *(const short8*)&T1buf[gi][kt * 512 + lane * 8];
        aA = mfma16(a1, wA[kt], aA);
      }
      stage_poll(pub2g[gi], T2buf[gi], (unsigned)t);  // tanh(h2[t])
      __syncthreads();
#pragma unroll
      for (int kt = 0; kt < 16; ++kt) {  // W12 x T2
        short8 a2 = *(const short8*)&T2buf[gi][kt * 512 + lane * 8];
        aB = mfma16(a2, wA[16 + kt], aB);
      }

      // rotated output for step t-1 of this group (wave gi on rotation block)
      if (t > 0 && slice == ((t - 1) & 7) && w == gi) {
        f32x4 ao = {0, 0, 0, 0};
#pragma unroll
        for (int kt = 0; kt < 16; ++kt) {
          short8 a2 = *(const short8*)&T2buf[gi][kt * 512 + lane * 8];
          short8 bo = *(const short8*)&WOlds[kt * 512 + lane * 8];
          ao = mfma16(a2, bo, ao);
        }
        if (c16 < 3) {
#pragma unroll
          for (int r = 0; r < 4; ++r)
            out[((size_t)(b0g[gi] + lrow0 + r) * TT + (t - 1)) * 3 + c16] = ao[r];
        }
      }

      unsigned short tp[4];
#pragma unroll
      for (int r = 0; r < 4; ++r) {
        float pre = aA[r] + aB[r]
                  + wis[0] * xstage[buf][gi][lrow0 + r][0]
                  + wis[1] * xstage[buf][gi][lrow0 + r][1]
                  + wis[2] * xstage[buf][gi][lrow0 + r][2]
                  + NOISE_S * n1v[r];
        float h = (1.0f - ALPHA) * h1[gi][r] + ALPHA * pre;
        h1[gi][r] = h;
        tp[r] = f2h(fast_tanh(h));
      }
#pragma unroll
      for (int r = 0; r < 4; ++r)
        __hip_atomic_store(&pub1g[gi][pslot + r * 8], tagN | tp[r],
                           __ATOMIC_RELAXED, __HIP_MEMORY_SCOPE_AGENT);
    }

    // ================= phase B: both chains =================
#pragma unroll
    for (int gi = 0; gi < 2; ++gi) {
      float n2v[4];
#pragma unroll
      for (int r = 0; r < 4; ++r)
        n2v[r] = noise2[((size_t)t * BB + b0g[gi] + lrow0 + r) * HH + n0 + c16];

      f32x4 bA = {0, 0, 0, 0}, bB = {0, 0, 0, 0};
#pragma unroll
      for (int kt = 0; kt < 16; ++kt) {  // W22 x T2 (stable across sync)
        short8 a2 = *(const short8*)&T2buf[gi][kt * 512 + lane * 8];
        bB = mfma16(a2, wB[16 + kt], bB);
      }
      stage_poll(pub1g[gi], T1buf[gi], (unsigned)(t + 1));  // fresh tanh(h1')
      if (gi == 1 && t + 1 < TT && tid < 160) {
        int gj = tid / 80, rem = tid % 80;
        int b = rem / 5, c = rem % 5;
        xstage[buf ^ 1][gj][b][c] = x[((size_t)(b0g[gj] + b) * TT + (t + 1)) * 5 + c];
      }
      __syncthreads();
#pragma unroll
      for (int kt = 0; kt < 16; ++kt) {  // W21 x fresh tanh(h1')
        short8 a1 = *(const short8*)&T1buf[gi][kt * 512 + lane * 8];
        bA = mfma16(a1, wB[kt], bA);
      }
      unsigned short tp[4];
#pragma unroll
      for (int r = 0; r < 4; ++r) {
        float pre = bA[r] + bB[r]
                  + wic[0] * xstage[buf][gi][lrow0 + r][3]
                  + wic[1] * xstage[buf][gi][lrow0 + r][4]
                  + NOISE_S * n2v[r];
        float h = (1.0f - ALPHA) * h2[gi][r] + ALPHA * pre;
        h2[gi][r] = h;
        tp[r] = f2h(fast_tanh(h));
      }
#pragma unroll
      for (int r = 0; r < 4; ++r)
        __hip_atomic_store(&pub2g[gi][pslot + r * 8], tagN | tp[r],
                           __ATOMIC_RELAXED, __HIP_MEMORY_SCOPE_AGENT);
    }
  }

  // ---- final output: out[TT-1] = tanh(h2[TT]) @ wo ----
  if (slice == ((TT - 1) & 7)) {
#pragma unroll
    for (int gi = 0; gi < 2; ++gi)
      stage_poll(pub2g[gi], T2buf[gi], (unsigned)TT);
    __syncthreads();
#pragma unroll
    for (int gi = 0; gi < 2; ++gi) {
      if (w == gi) {
        f32x4 ao = {0, 0, 0, 0};
#pragma unroll
        for (int kt = 0; kt < 16; ++kt) {
          short8 a2 = *(const short8*)&T2buf[gi][kt * 512 + lane * 8];
          short8 bo = *(const short8*)&WOlds[kt * 512 + lane * 8];
          ao = mfma16(a2, bo, ao);
        }
        if (c16 < 3) {
#pragma unroll
          for (int r = 0; r < 4; ++r)
            out[((size_t)(b0g[gi] + lrow0 + r) * TT + (TT - 1)) * 3 + c16] = ao[r];
        }
      }
    }
  }
}

extern "C" void kernel_launch(void* const* d_in, const int* in_sizes, int n_in,
                              void* d_out, int out_size, void* d_ws, size_t ws_size,
                              hipStream_t stream) {
  const float* x       = (const float*)d_in[0];
  const float* wi_stim = (const float*)d_in[1];
  const float* w11     = (const float*)d_in[2];
  const float* wi_ctx  = (const float*)d_in[3];
  const float* w22     = (const float*)d_in[4];
  const float* w12     = (const float*)d_in[5];
  const float* w21     = (const float*)d_in[6];
  const float* wo      = (const float*)d_in[7];
  const float* n1      = (const float*)d_in[8];
  const float* n2      = (const float*)d_in[9];
  char* ws = (char*)d_ws;                  // needs ~2.7 MB

  int nz = (NGROUP * 32768 * 2) / 4;       // pub1+pub2 words
  zero_ws<<<64, 256, 0, stream>>>((int*)(ws + PUB1_B), nz);
  pack_weights<<<516, 256, 0, stream>>>(w11, w12, w21, w22, wo,
                                        (unsigned short*)ws);
  rnn_main<<<NSLICE * (NGROUP / GPB), 256, 0, stream>>>(x, wi_stim, wi_ctx,
                                                        n1, n2, ws, (float*)d_out);
}